// Round 15
// baseline (129.277 us; speedup 1.0000x reference)
//
#include <hip/hip_runtime.h>

#define BATCH 16
#define PS 49                // nodes per partition (fits 6-bit match-any)
#define NPART 1024           // 1024*49 = 50176 >= 50001
#define SB 256               // hist/scatter blocks
#define TPB 1024
#define LDSCAP 3840          // records staged in LDS (mean 3136, +12.6 sigma); 61440 B

// fast tanh: 1 - 2/(e^{2z}+1); rel err ~1e-6 vs 2.6e-4 threshold
static __device__ __forceinline__ float fast_tanh(float z) {
    float ez = __expf(2.0f * z);
    return 1.0f - 2.0f * __builtin_amdgcn_rcpf(ez + 1.0f);
}

// Same-value lane mask over 6-bit keys via bit-ballots (match-any).
static __device__ __forceinline__ unsigned long long match6(unsigned o) {
    unsigned long long m = ~0ull;
#pragma unroll
    for (int b = 0; b < 6; ++b) {
        unsigned long long bb = __ballot((o >> b) & 1u);
        m &= ((o >> b) & 1u) ? bb : ~bb;
    }
    return m;
}

// Histogram of OWNER-endpoint partitions (2 records per edge) + fused aux build.
__global__ __launch_bounds__(TPB)
void hist1(const int* __restrict__ src, const int* __restrict__ des,
           const float* __restrict__ x, float* __restrict__ auxT,
           unsigned* __restrict__ blockHist, int E, int n) {
    __shared__ unsigned h[NPART];
    int tid = threadIdx.x;
    for (int i = tid; i < NPART; i += TPB) h[i] = 0;
    // fused: build aux_T[(N+1)][16] (consumed by a later kernel; no intra-kernel dep)
    for (long idx = (long)blockIdx.x * TPB + tid; idx < (long)BATCH * n;
         idx += (long)gridDim.x * TPB) {
        int b = (int)(idx / n);
        int i = (int)(idx - (long)b * n);
        auxT[(size_t)(i + 1) * BATCH + b] = x[idx];
        if (idx < BATCH) auxT[idx] = 0.0f;
    }
    __syncthreads();
    long t = (long)blockIdx.x * TPB + tid;
    long stride = (long)gridDim.x * TPB * 4;
    for (long e0 = t * 4; e0 < E; e0 += stride) {
        int ne = (int)min((long)4, (long)E - e0);
        int ss[4], dd[4];
        if (ne == 4) {
            int4 sv = *(const int4*)(src + e0);
            int4 dv = *(const int4*)(des + e0);
            ss[0]=sv.x; ss[1]=sv.y; ss[2]=sv.z; ss[3]=sv.w;
            dd[0]=dv.x; dd[1]=dv.y; dd[2]=dv.z; dd[3]=dv.w;
        } else {
            for (int j = 0; j < ne; ++j) { ss[j] = src[e0+j]; dd[j] = des[e0+j]; }
        }
        for (int j = 0; j < ne; ++j) {
            atomicAdd(&h[ss[j] / PS], 1u);
            atomicAdd(&h[dd[j] / PS], 1u);
        }
    }
    __syncthreads();
    for (int i = tid; i < NPART; i += TPB)
        blockHist[(size_t)blockIdx.x * NPART + i] = h[i];
}

// Grid-parallel per-bin totals: 64 bins/block x 16 threads. Grid = NPART/64 = 16.
__global__ __launch_bounds__(TPB)
void totals_k(const unsigned* __restrict__ blockHist, unsigned* __restrict__ binTotal) {
    int tid = threadIdx.x;
    int bin = blockIdx.x * 64 + (tid >> 4);
    int j = tid & 15;
    unsigned s = 0;
    for (int r = j; r < SB; r += 16) s += blockHist[(size_t)r * NPART + bin];
#pragma unroll
    for (int m = 1; m < 16; m <<= 1) s += __shfl_xor(s, m, 64);
    if (j == 0) binTotal[bin] = s;
}

// One block: exclusive scan of 1024 bin totals -> partStart[0..1024].
__global__ __launch_bounds__(TPB)
void scan_bins(const unsigned* __restrict__ binTotal, unsigned* __restrict__ partStart) {
    __shared__ unsigned wsum[16];
    int tid = threadIdx.x;
    int lane = tid & 63, wv = tid >> 6;
    unsigned v = binTotal[tid];
    unsigned inc = v;
    for (int off = 1; off < 64; off <<= 1) {
        unsigned t = __shfl_up(inc, off, 64);
        if (lane >= off) inc += t;
    }
    if (lane == 63) wsum[wv] = inc;
    __syncthreads();
    if (tid < 16) {
        unsigned w = wsum[tid], winc = w;
        for (int off = 1; off < 16; off <<= 1) {
            unsigned t = __shfl_up(winc, off, 64);
            if (tid >= off) winc += t;
        }
        wsum[tid] = winc - w;
    }
    __syncthreads();
    unsigned excl = (inc - v) + wsum[wv];
    partStart[tid] = excl;
    if (tid == TPB - 1) partStart[NPART] = excl + v;
}

// Grid-parallel: blockHist -> per-(block,bin) scatter offsets. 64 bins/block x 16.
__global__ __launch_bounds__(TPB)
void offs_k(unsigned* __restrict__ blockHist, const unsigned* __restrict__ partStart) {
    int tid = threadIdx.x;
    int binLocal = tid >> 4;
    int bin = blockIdx.x * 64 + binLocal;
    int j = tid & 15;
    const int per = SB / 16;
    unsigned ls = 0;
    for (int r = j * per; r < (j + 1) * per; ++r)
        ls += blockHist[(size_t)r * NPART + bin];
    int waveBase = (binLocal & 3) * 16;
    unsigned excl = 0;
    for (int k = 0; k < 16; ++k) {
        unsigned v = __shfl(ls, waveBase + k, 64);
        if (k < j) excl += v;
    }
    unsigned run = partStart[bin] + excl;
    for (int r = j * per; r < (j + 1) * per; ++r) {
        unsigned tmp = blockHist[(size_t)r * NPART + bin];
        blockHist[(size_t)r * NPART + bin] = run;
        run += tmp;
    }
}

// Emit 2 owner-endpoint records per edge, signs folded into (a,w):
//   owner=s: {s|d<<16, -a, +w, c};  owner=d: {d|s<<16, +a, -w, c}
__global__ __launch_bounds__(TPB)
void scatter1(const int* __restrict__ src, const int* __restrict__ des,
              const float* __restrict__ param, const unsigned* __restrict__ offsets,
              uint4* __restrict__ bins, int E) {
    __shared__ unsigned offs[NPART];
    int tid = threadIdx.x;
    for (int i = tid; i < NPART; i += TPB)
        offs[i] = offsets[(size_t)blockIdx.x * NPART + i];
    __syncthreads();
    long t = (long)blockIdx.x * TPB + tid;
    long stride = (long)gridDim.x * TPB * 4;
    for (long e0 = t * 4; e0 < E; e0 += stride) {
        int ne = (int)min((long)4, (long)E - e0);
        int ss[4], dd[4];
        float aa[4], ww[4], cc[4];
        if (ne == 4) {
            int4 sv = *(const int4*)(src + e0);
            int4 dv = *(const int4*)(des + e0);
            float4 av = *(const float4*)(param + e0);
            float4 wv = *(const float4*)(param + E + e0);
            float4 cv = *(const float4*)(param + 2 * (size_t)E + e0);
            ss[0]=sv.x; ss[1]=sv.y; ss[2]=sv.z; ss[3]=sv.w;
            dd[0]=dv.x; dd[1]=dv.y; dd[2]=dv.z; dd[3]=dv.w;
            aa[0]=av.x; aa[1]=av.y; aa[2]=av.z; aa[3]=av.w;
            ww[0]=wv.x; ww[1]=wv.y; ww[2]=wv.z; ww[3]=wv.w;
            cc[0]=cv.x; cc[1]=cv.y; cc[2]=cv.z; cc[3]=cv.w;
        } else {
            for (int j = 0; j < ne; ++j) {
                ss[j] = src[e0+j]; dd[j] = des[e0+j];
                aa[j] = param[e0+j]; ww[j] = param[E + e0 + j];
                cc[j] = param[2 * (size_t)E + e0 + j];
            }
        }
        for (int j = 0; j < ne; ++j) {
            int s = ss[j], d = dd[j];
            unsigned slot = atomicAdd(&offs[s / PS], 1u);
            bins[slot] = make_uint4((unsigned)s | ((unsigned)d << 16),
                                    __float_as_uint(-aa[j]), __float_as_uint(ww[j]),
                                    __float_as_uint(cc[j]));
            unsigned slot2 = atomicAdd(&offs[d / PS], 1u);
            bins[slot2] = make_uint4((unsigned)d | ((unsigned)s << 16),
                                     __float_as_uint(aa[j]), __float_as_uint(-ww[j]),
                                     __float_as_uint(cc[j]));
        }
    }
}

// Fused sort+accumulate: one block per partition. Match-any aggregated claims:
// only the leader lane of each same-owner group issues the LDS atomic.
__global__ __launch_bounds__(TPB)
void sort_accumulate(const uint4* __restrict__ bins, const unsigned* __restrict__ partStart,
                     const float* __restrict__ auxT, float* __restrict__ outT, int n) {
    extern __shared__ uint4 srec[];                 // [LDSCAP]
    unsigned* ns  = (unsigned*)(srec + LDSCAP);     // [PS+1]
    unsigned* cnt = ns + (PS + 1);                  // [64] counts, then claim cursors
    int p = blockIdx.x;
    int tid = threadIdx.x;
    int lane = tid & 63;
    int wv = tid >> 6;
    unsigned lo = partStart[p], hi = partStart[p + 1];
    unsigned cl = min(hi - lo, (unsigned)LDSCAP);
    int base = p * PS;

    if (tid < 64) cnt[tid] = 0;
    __syncthreads();
    // pass 1: aggregated count by owner node (keys only; leader-lane atomics)
    const unsigned* keys = (const unsigned*)bins;
    for (unsigned kb = (unsigned)(wv * 64); kb < cl; kb += TPB) {
        unsigned k = kb + (unsigned)lane;
        unsigned o = 63u;
        if (k < cl) o = (keys[(size_t)(lo + k) * 4] & 0xFFFFu) - (unsigned)base;
        unsigned long long m = match6(o);
        int leader = __ffsll((long long)m) - 1;
        if (lane == leader && o < (unsigned)PS)
            atomicAdd(&cnt[o], (unsigned)__popcll(m));
    }
    __syncthreads();
    if (tid == 0) {
        unsigned run = 0;
        for (int i = 0; i < PS; ++i) { unsigned c = cnt[i]; ns[i] = run; run += c; }
        ns[PS] = run;
    }
    __syncthreads();
    if (tid < PS) cnt[tid] = ns[tid];   // claim cursors
    if (tid == 63) cnt[63] = 0;         // trash slot for invalid lanes
    __syncthreads();
    // pass 2: aggregated scatter bin -> LDS sorted (bin L2-hot from pass 1)
    for (unsigned kb = (unsigned)(wv * 64); kb < cl; kb += TPB) {
        unsigned k = kb + (unsigned)lane;
        uint4 rec = make_uint4(0u, 0u, 0u, 0u);
        unsigned o = 63u;
        if (k < cl) { rec = bins[lo + k]; o = (rec.x & 0xFFFFu) - (unsigned)base; }
        unsigned long long m = match6(o);
        int leader = __ffsll((long long)m) - 1;
        unsigned bpos = 0;
        if (lane == leader) bpos = atomicAdd(&cnt[o], (unsigned)__popcll(m));
        bpos = __shfl(bpos, leader, 64);
        if (k < cl) {
            unsigned rank = (unsigned)__popcll(m & ((1ull << lane) - 1ull));
            srec[bpos + rank] = rec;
        }
    }
    __syncthreads();
    // pass 3: wave per node, 16 records in flight, lane-quad owns 4 batches
    int ri = lane >> 2, lj = lane & 3;
    const float4* aux4 = (const float4*)auxT;
    float4* out4 = (float4*)outT;
    for (int nl = wv; nl < PS; nl += TPB / 64) {
        int node = base + nl;
        if (node == 0 || node > n) continue;
        unsigned l2 = ns[nl], h2 = ns[nl + 1];
        float4 vo = aux4[(size_t)node * 4 + lj];
        float ax = 0.0f, ay = 0.0f, az = 0.0f, as_ = 0.0f;
        for (unsigned kk = l2; kk < h2; kk += 16) {
            unsigned k = kk + (unsigned)ri;
            uint4 rec;
            if (k < h2) rec = srec[k];
            else { rec.x = 0u; rec.y = 0u; rec.z = 0u; rec.w = 0u; }
            unsigned rem = rec.x >> 16;
            float4 vr = aux4[(size_t)rem * 4 + lj];
            float a = __uint_as_float(rec.y);
            float w = __uint_as_float(rec.z);
            float c = __uint_as_float(rec.w);
            ax  += a * fast_tanh(w * (vo.x - vr.x) + c);
            ay  += a * fast_tanh(w * (vo.y - vr.y) + c);
            az  += a * fast_tanh(w * (vo.z - vr.z) + c);
            as_ += a * fast_tanh(w * (vo.w - vr.w) + c);
        }
        // overflow tail (normally empty): filtered scan of un-staged records
        for (unsigned kk = lo + cl; kk < hi; kk += 16) {
            unsigned k = kk + (unsigned)ri;
            uint4 rec;
            if (k < hi) rec = bins[k];
            else { rec.x = 0u; rec.y = 0u; rec.z = 0u; rec.w = 0u; }
            if ((int)(rec.x & 0xFFFFu) != node) rec.y = 0u;   // a=0 -> no contribution
            unsigned rem = rec.x >> 16;
            float4 vr = aux4[(size_t)rem * 4 + lj];
            float a = __uint_as_float(rec.y);
            float w = __uint_as_float(rec.z);
            float c = __uint_as_float(rec.w);
            ax  += a * fast_tanh(w * (vo.x - vr.x) + c);
            ay  += a * fast_tanh(w * (vo.y - vr.y) + c);
            az  += a * fast_tanh(w * (vo.z - vr.z) + c);
            as_ += a * fast_tanh(w * (vo.w - vr.w) + c);
        }
#pragma unroll
        for (int m = 4; m < 64; m <<= 1) {
            ax  += __shfl_xor(ax, m, 64);
            ay  += __shfl_xor(ay, m, 64);
            az  += __shfl_xor(az, m, 64);
            as_ += __shfl_xor(as_, m, 64);
        }
        if (lane < 4)
            out4[(size_t)node * 4 + lane] = make_float4(ax, ay, az, as_);
    }
}

// out[b][j] = outT[j+1][b]  (drops node 0)
__global__ void transpose_out(const float* __restrict__ outT, float* __restrict__ out, int n) {
    int idx = blockIdx.x * blockDim.x + threadIdx.x;
    if (idx >= BATCH * n) return;
    int b = idx / n;
    int j = idx % n;
    out[idx] = outT[(size_t)(j + 1) * BATCH + b];
}

// ---------------- fallback: direct device atomics ----------------
__global__ void edge_direct(const float* __restrict__ param,
                            const int* __restrict__ src,
                            const int* __restrict__ des,
                            const float* __restrict__ x,
                            float* __restrict__ out, int E, int n) {
    int e = blockIdx.x * blockDim.x + threadIdx.x;
    if (e >= E) return;
    float a = param[e], w = param[E + e], c = param[2 * E + e];
    int s = src[e], d = des[e];
#pragma unroll
    for (int b = 0; b < BATCH; ++b) {
        float vs = s ? x[(size_t)b * n + (s - 1)] : 0.0f;
        float vd = d ? x[(size_t)b * n + (d - 1)] : 0.0f;
        float st = a * tanhf(w * (vs - vd) + c);
        if (s) atomicAdd(out + (size_t)b * n + (s - 1), -st);
        if (d) atomicAdd(out + (size_t)b * n + (d - 1), st);
    }
}

extern "C" void kernel_launch(void* const* d_in, const int* in_sizes, int n_in,
                              void* d_out, int out_size, void* d_ws, size_t ws_size,
                              hipStream_t stream) {
    const float* x     = (const float*)d_in[1];
    const float* param = (const float*)d_in[2];
    const int*   src   = (const int*)d_in[3];
    const int*   des   = (const int*)d_in[4];
    float* out = (float*)d_out;

    int E = in_sizes[3];
    int n = in_sizes[1] / BATCH;   // N = 50000
    int total = BATCH * n;

    auto alignup = [](size_t v) { return (v + 255) & ~(size_t)255; };
    size_t auxBytes  = alignup((size_t)(n + 1) * BATCH * sizeof(float));
    size_t outTBytes = auxBytes;
    size_t bhBytes   = alignup((size_t)SB * NPART * sizeof(unsigned));
    size_t psBytes   = alignup((size_t)(NPART + 1) * sizeof(unsigned));
    size_t btBytes   = alignup((size_t)NPART * sizeof(unsigned));
    size_t binBytes  = alignup((size_t)2 * E * sizeof(uint4));
    size_t need      = auxBytes + outTBytes + bhBytes + psBytes + btBytes + binBytes;

    size_t saLds = (size_t)LDSCAP * sizeof(uint4) + (PS + 1 + 64) * sizeof(unsigned);

    if (ws_size >= need && (n + 1) <= NPART * PS && n <= 65534) {
        char* w = (char*)d_ws;
        float*    auxT      = (float*)w;     w += auxBytes;
        float*    outT      = (float*)w;     w += outTBytes;
        unsigned* blockHist = (unsigned*)w;  w += bhBytes;
        unsigned* partStart = (unsigned*)w;  w += psBytes;
        unsigned* binTotal  = (unsigned*)w;  w += btBytes;
        uint4*    bins      = (uint4*)w;

        hist1<<<SB, TPB, 0, stream>>>(src, des, x, auxT, blockHist, E, n);
        totals_k<<<NPART / 64, TPB, 0, stream>>>(blockHist, binTotal);
        scan_bins<<<1, TPB, 0, stream>>>(binTotal, partStart);
        offs_k<<<NPART / 64, TPB, 0, stream>>>(blockHist, partStart);
        scatter1<<<SB, TPB, 0, stream>>>(src, des, param, blockHist, bins, E);
        sort_accumulate<<<NPART, TPB, saLds, stream>>>(bins, partStart, auxT, outT, n);
        transpose_out<<<(total + 255) / 256, 256, 0, stream>>>(outT, out, n);
        return;
    }

    (void)hipMemsetAsync(out, 0, (size_t)out_size * sizeof(float), stream);
    edge_direct<<<(E + 255) / 256, 256, 0, stream>>>(param, src, des, x, out, E, n);
}